// Round 12
// baseline (390.167 us; speedup 1.0000x reference)
//
#include <hip/hip_runtime.h>

#define WS_ALIGN(x) (((x) + size_t(255)) & ~size_t(255))

typedef unsigned int uint;
typedef unsigned short ushort;
typedef __attribute__((ext_vector_type(8))) short short8;
typedef __attribute__((ext_vector_type(4))) float floatx4;
typedef __attribute__((ext_vector_type(2))) float f32x2;   // v_pk_*_f32

#define SHIFT 9          // 512 nodes per coarse bucket
#define NPB   (1 << SHIFT)
#define CRB   1024       // col-reduce stage-1 blocks

__device__ __forceinline__ ushort f2bf(float f) {
    uint u = __float_as_uint(f);
    return (ushort)((u + 0x7fff + ((u >> 16) & 1)) >> 16);  // RNE
}
__device__ __forceinline__ float bflo(uint u) { return __uint_as_float(u << 16); }
__device__ __forceinline__ float bfhi(uint u) { return __uint_as_float(u & 0xffff0000u); }

// ---------------- CSR build: LDS-radix partition (no global atomics on CSR) --
// Requires N <= 131072 (src packs in 17 bits) and NB <= 256.
// R11: per-node degree counted here via global atomics (deg pre-zeroed) so
// dinv is derivable (rsqrtf(deg+1)) BEFORE p2_csr -> gemm1 can overlap place.

__global__ __launch_bounds__(256) void p1_hist(const int* __restrict__ dst, int E,
                                               int chunk, int NB, int* __restrict__ ghist,
                                               int* __restrict__ deg) {
    __shared__ int h[256];
    h[threadIdx.x] = 0;
    __syncthreads();
    int e0 = blockIdx.x * chunk, e1 = min(E, e0 + chunk);
    for (int e = e0 + threadIdx.x; e < e1; e += 256) {
        int d = dst[e];
        atomicAdd(&h[d >> SHIFT], 1);
        atomicAdd(&deg[d], 1);
    }
    __syncthreads();
    if ((int)threadIdx.x < NB) ghist[blockIdx.x * NB + threadIdx.x] = h[threadIdx.x];
}

// block c: exclusive prefix down column c of ghist[NB][NB]; total -> tot[c]
__global__ __launch_bounds__(256) void p1_colscan(int* __restrict__ ghist, int NB,
                                                  int* __restrict__ tot) {
    __shared__ int lds[256];
    int c = blockIdx.x, t = threadIdx.x;
    int v = (t < NB) ? ghist[t * NB + c] : 0;
    lds[t] = v;
    __syncthreads();
    for (int o = 1; o < 256; o <<= 1) {
        int u = (t >= o) ? lds[t - o] : 0;
        __syncthreads();
        if (t >= o) lds[t] += u;
        __syncthreads();
    }
    if (t < NB) ghist[t * NB + c] = lds[t] - v;  // exclusive over blocks
    if (t == 255) tot[c] = lds[255];
}

// ---------------- MFMA bf16 GEMM body (K=128), W staged from f32 directly ---
// (wconv kernel deleted R11: each block transposes W f32->bf16 into LDS;
//  W is L2-hot 32-64KB so the extra reads are ~free.)
// ABF16: A is bf16 [M][128]. dinv computed inline from deg (rsqrtf(deg+1)).

template <int TN, bool BN, bool ABF16>
__device__ __forceinline__ void gemm_body(int bid, char* smem,
                                          const void* __restrict__ Araw,
                                          const float* __restrict__ Wf,
                                          const float* __restrict__ scale,
                                          const float* __restrict__ shift,
                                          const int* __restrict__ deg,
                                          ushort* __restrict__ Cb, int M) {
    constexpr int TM = 64;
    constexpr int PK = 136;  // padded row stride in shorts: 272 B (16B-aligned)
    constexpr int NCT = TN / 16;
    ushort* Ab = (ushort*)smem;            // TM*PK shorts
    ushort* Wl = Ab + TM * PK;             // TN*PK shorts
    int tid = threadIdx.x;
    int wave = tid >> 6, lane = tid & 63;
    int rowBase = bid * TM;

    // W staging: Wl[n*PK+k] = bf16(Wf[k*TN+n]); lanes consecutive in n -> coalesced
    for (int l = tid; l < TN * 16; l += 256) {
        int n = l % TN;
        int cg = (l / TN) * 8;
        float w[8];
#pragma unroll
        for (int j = 0; j < 8; ++j) w[j] = Wf[(cg + j) * TN + n];
        uint4 pw;
        pw.x = (uint)f2bf(w[0]) | ((uint)f2bf(w[1]) << 16);
        pw.y = (uint)f2bf(w[2]) | ((uint)f2bf(w[3]) << 16);
        pw.z = (uint)f2bf(w[4]) | ((uint)f2bf(w[5]) << 16);
        pw.w = (uint)f2bf(w[6]) | ((uint)f2bf(w[7]) << 16);
        *(uint4*)&Wl[n * PK + cg] = pw;
    }
    if constexpr (ABF16) {
        const ushort* A = (const ushort*)Araw;
        for (int l = tid; l < TM * 16; l += 256) {
            int r = l >> 4, c = (l & 15) << 3;   // 8 bf16 per thread
            int gr = rowBase + r;
            uint4 v = make_uint4(0, 0, 0, 0);
            if (gr < M) v = *(const uint4*)&A[(size_t)gr * 128 + c];
            if (BN) {
                uint w[4] = {v.x, v.y, v.z, v.w};
                uint o[4];
#pragma unroll
                for (int k = 0; k < 4; ++k) {
                    float f0 = fmaxf(fmaf(bflo(w[k]), scale[c + 2 * k], shift[c + 2 * k]), 0.f);
                    float f1 = fmaxf(fmaf(bfhi(w[k]), scale[c + 2 * k + 1], shift[c + 2 * k + 1]), 0.f);
                    o[k] = (uint)f2bf(f0) | ((uint)f2bf(f1) << 16);
                }
                v = make_uint4(o[0], o[1], o[2], o[3]);
            }
            *(uint4*)&Ab[r * PK + c] = v;
        }
    } else {
        const float* A = (const float*)Araw;
        for (int l = tid; l < TM * 32; l += 256) {
            int r = l >> 5, c = (l & 31) << 2;
            int gr = rowBase + r;
            float4 v = make_float4(0.f, 0.f, 0.f, 0.f);
            if (gr < M) v = *(const float4*)&A[(size_t)gr * 128 + c];
            if (BN) {
                v.x = fmaxf(fmaf(v.x, scale[c + 0], shift[c + 0]), 0.f);
                v.y = fmaxf(fmaf(v.y, scale[c + 1], shift[c + 1]), 0.f);
                v.z = fmaxf(fmaf(v.z, scale[c + 2], shift[c + 2]), 0.f);
                v.w = fmaxf(fmaf(v.w, scale[c + 3], shift[c + 3]), 0.f);
            }
            uint2 p;
            p.x = (uint)f2bf(v.x) | ((uint)f2bf(v.y) << 16);
            p.y = (uint)f2bf(v.z) | ((uint)f2bf(v.w) << 16);
            *(uint2*)&Ab[r * PK + c] = p;
        }
    }
    __syncthreads();

    floatx4 acc[NCT];
#pragma unroll
    for (int ct = 0; ct < NCT; ++ct) acc[ct] = (floatx4){0.f, 0.f, 0.f, 0.f};

    int m = wave * 16 + (lane & 15);
    int quad = lane >> 4;
#pragma unroll
    for (int kc = 0; kc < 128; kc += 32) {
        int k0 = kc + quad * 8;
        short8 a = *(const short8*)&Ab[m * PK + k0];
#pragma unroll
        for (int ct = 0; ct < NCT; ++ct) {
            short8 b = *(const short8*)&Wl[(ct * 16 + (lane & 15)) * PK + k0];
            acc[ct] = __builtin_amdgcn_mfma_f32_16x16x32_bf16(a, b, acc[ct], 0, 0, 0);
        }
    }

    int r0 = rowBase + wave * 16 + quad * 4;
    int col0 = lane & 15;
#pragma unroll
    for (int r = 0; r < 4; ++r) {
        int gr = r0 + r;
        if (gr < M) {
            float dv = rsqrtf((float)(deg[gr] + 1));
#pragma unroll
            for (int ct = 0; ct < NCT; ++ct)
                Cb[(size_t)gr * TN + ct * 16 + col0] = f2bf(acc[ct][r] * dv);
        }
    }
}

// ---------------- merged: p1_place (blocks 0..NB-1) ∥ gemm1 (rest) --------
// place needs only ghist/tot (ready); gemm1 needs x, W1, deg (ready after
// p1_hist). bbase recomputed in-LDS from tot (p1_base kernel deleted).

__global__ __launch_bounds__(256) void k_place_gemm1(
        const int* __restrict__ src, const int* __restrict__ dst, int E,
        int chunk, int NB, const int* __restrict__ ghist,
        const int* __restrict__ tot, int* __restrict__ parts,
        const float* __restrict__ x, const float* __restrict__ W1,
        const int* __restrict__ deg, ushort* __restrict__ h1b, int M) {
    __shared__ __align__(16) char smem[(64 + 128) * 136 * 2];  // 52224 B
    if ((int)blockIdx.x < NB) {
        int* h    = (int*)smem;        // 256
        int* base = h + 256;           // 256
        int* lds  = base + 256;        // 256 (tot scan)
        int t = threadIdx.x;
        int v = (t < NB) ? tot[t] : 0;
        lds[t] = v;
        __syncthreads();
        for (int o = 1; o < 256; o <<= 1) {
            int u = (t >= o) ? lds[t - o] : 0;
            __syncthreads();
            if (t >= o) lds[t] += u;
            __syncthreads();
        }
        h[t] = 0;
        if (t < NB) base[t] = (lds[t] - v) + ghist[blockIdx.x * NB + t];
        __syncthreads();
        int e0 = blockIdx.x * chunk, e1 = min(E, e0 + chunk);
        for (int e = e0 + t; e < e1; e += 256) {
            int d = dst[e];
            int b = d >> SHIFT;
            int local = atomicAdd(&h[b], 1);
            parts[base[b] + local] = src[e] | ((d & (NPB - 1)) << 17);
        }
    } else {
        gemm_body<128, false, false>((int)blockIdx.x - NB, smem, x, W1,
                                     nullptr, nullptr, deg, h1b, M);
    }
}

__global__ __launch_bounds__(256) void k_gemm2(const ushort* __restrict__ A,
                                               const float* __restrict__ W2,
                                               const float* __restrict__ scale,
                                               const float* __restrict__ shift,
                                               const int* __restrict__ deg,
                                               ushort* __restrict__ Cb, int M) {
    __shared__ __align__(16) char smem[(64 + 64) * 136 * 2];  // 34816 B
    gemm_body<64, true, true>((int)blockIdx.x, smem, A, W2, scale, shift, deg, Cb, M);
}

// one block per bucket: local count -> scan -> CSR place; start/cnt per node.
// bbase[b], bbase[b+1] derived from in-LDS scan of tot (p1_base deleted).
__global__ __launch_bounds__(256) void p2_csr(const int* __restrict__ parts,
                                              const int* __restrict__ tot, int NB, int N,
                                              int* __restrict__ nodeStart,
                                              int* __restrict__ nodeCnt,
                                              int* __restrict__ esrc) {
    __shared__ int cnt[NPB], off[NPB], cur[NPB];
    __shared__ int pair[256];
    __shared__ int sE0, sE1;
    int b = blockIdx.x, t = threadIdx.x;
    int n0 = b << SHIFT;
    {   // inclusive scan of tot -> e0 = incl[b]-tot[b], e1 = incl[b]
        int v = (t < NB) ? tot[t] : 0;
        pair[t] = v;
        __syncthreads();
        for (int o = 1; o < 256; o <<= 1) {
            int u = (t >= o) ? pair[t - o] : 0;
            __syncthreads();
            if (t >= o) pair[t] += u;
            __syncthreads();
        }
        if (t == b) { sE1 = pair[t]; sE0 = pair[t] - v; }
        __syncthreads();
    }
    int e0 = sE0, e1 = sE1;
    cnt[t] = 0;
    cnt[t + 256] = 0;
    cur[t] = 0;
    cur[t + 256] = 0;
    __syncthreads();
    for (int e = e0 + t; e < e1; e += 256)
        atomicAdd(&cnt[(parts[e] >> 17) & (NPB - 1)], 1);
    __syncthreads();
    int psum = cnt[2 * t] + cnt[2 * t + 1];
    pair[t] = psum;
    __syncthreads();
    for (int o = 1; o < 256; o <<= 1) {
        int u = (t >= o) ? pair[t - o] : 0;
        __syncthreads();
        if (t >= o) pair[t] += u;
        __syncthreads();
    }
    int excl = pair[t] - psum;
    off[2 * t] = excl;
    off[2 * t + 1] = excl + cnt[2 * t];
    __syncthreads();
#pragma unroll
    for (int j = t; j < NPB; j += 256) {
        int n = n0 + j;
        if (n < N) {
            nodeStart[n] = e0 + off[j];
            nodeCnt[n] = cnt[j];
        }
    }
    for (int e = e0 + t; e < e1; e += 256) {
        int p = parts[e];
        int dl = (p >> 17) & (NPB - 1);
        int local = atomicAdd(&cur[dl], 1);
        esrc[e0 + off[dl] + local] = p & 0x1FFFF;
    }
}

// ---------------- SpMM: unweighted gather-sum of hs rows, scale by dinv ----
// R5 structure (proven best) + R8 packed-f32 accumulation; agg bf16 (R9/R10);
// dinv computed inline from nodeCnt (R11: dinv array deleted).

__global__ __launch_bounds__(256) void spmm128(const ushort* __restrict__ hb,
                                               const int* __restrict__ nodeStart,
                                               const int* __restrict__ nodeCnt,
                                               const int* __restrict__ esrc,
                                               ushort* __restrict__ out, int N) {
    int node = blockIdx.x * 4 + (threadIdx.x >> 6);
    if (node >= N) return;
    int lane = threadIdx.x & 63;
    int par = lane >> 5;          // 0: even edges, 1: odd edges
    int cb = (lane & 31) << 3;    // byte offset of this lane's uint2 column
    const char* hbase = (const char*)hb;  // row = 256 B
    uint2 sv = *(const uint2*)(hbase + (((uint)node << 8) + cb));
    f32x2 aA, aB;                 // even chain {f0,f1},{f2,f3} (+ self on par 0)
    if (par == 0) {
        aA = (f32x2){bflo(sv.x), bfhi(sv.x)};
        aB = (f32x2){bflo(sv.y), bfhi(sv.y)};
    } else {
        aA = (f32x2){0.f, 0.f};
        aB = (f32x2){0.f, 0.f};
    }
    f32x2 bA = {0.f, 0.f}, bB = {0.f, 0.f};  // odd chain (ILP)
    int cnt = nodeCnt[node];
    float dv = rsqrtf((float)(cnt + 1));
    const int* bp = esrc + nodeStart[node];
    int e = 0;
    if (cnt >= 16) {
        int s[8];
#pragma unroll
        for (int j = 0; j < 8; ++j) s[j] = bp[2 * j + par];
        while (true) {
            int sn[8];
#pragma unroll
            for (int j = 0; j < 8; ++j) sn[j] = bp[e + 16 + 2 * j + par];  // padded
            uint2 u[8];
#pragma unroll
            for (int j = 0; j < 8; ++j)
                u[j] = *(const uint2*)(hbase + (((uint)s[j] << 8) + cb));
#pragma unroll
            for (int j = 0; j < 8; ++j) {
                f32x2 lo = {bflo(u[j].x), bfhi(u[j].x)};
                f32x2 hi = {bflo(u[j].y), bfhi(u[j].y)};
                if (j & 1) { bA += lo; bB += hi; }
                else       { aA += lo; aB += hi; }
            }
            e += 16;
            if (e + 16 > cnt) break;
#pragma unroll
            for (int j = 0; j < 8; ++j) s[j] = sn[j];
        }
    }
    if (e < cnt) {  // batched predicated tail: one parallel round trip
        int last = cnt - 1;
        int s[8];
#pragma unroll
        for (int j = 0; j < 8; ++j) {
            int o = e + 2 * j + par;
            s[j] = bp[o < cnt ? o : last];
        }
        uint2 u[8];
#pragma unroll
        for (int j = 0; j < 8; ++j)
            u[j] = *(const uint2*)(hbase + (((uint)s[j] << 8) + cb));
#pragma unroll
        for (int j = 0; j < 8; ++j) {
            float m = ((e + 2 * j + par) < cnt) ? 1.f : 0.f;
            f32x2 mm = {m, m};
            f32x2 lo = {bflo(u[j].x), bfhi(u[j].x)};
            f32x2 hi = {bflo(u[j].y), bfhi(u[j].y)};
            if (j & 1) { bA += lo * mm; bB += hi * mm; }
            else       { aA += lo * mm; aB += hi * mm; }
        }
    }
    aA += bA;
    aB += bB;
    float r0 = aA.x, r1 = aA.y, r2 = aB.x, r3 = aB.y;
    r0 += __shfl_xor(r0, 32);
    r1 += __shfl_xor(r1, 32);
    r2 += __shfl_xor(r2, 32);
    r3 += __shfl_xor(r3, 32);
    if (par == 0) {
        uint2 pk;
        pk.x = (uint)f2bf(dv * r0) | ((uint)f2bf(dv * r1) << 16);
        pk.y = (uint)f2bf(dv * r2) | ((uint)f2bf(dv * r3) << 16);
        ((uint2*)out)[(size_t)node * 32 + (lane & 31)] = pk;
    }
}

__global__ __launch_bounds__(256) void spmm64(const ushort* __restrict__ hb,
                                              const int* __restrict__ nodeStart,
                                              const int* __restrict__ nodeCnt,
                                              const int* __restrict__ esrc,
                                              ushort* __restrict__ out, int N) {
    int node = blockIdx.x * 4 + (threadIdx.x >> 6);
    if (node >= N) return;
    int lane = threadIdx.x & 63;
    int par = lane >> 5;          // 0: even edges, 1: odd edges
    int cb = (lane & 31) << 2;    // byte offset of this lane's uint column
    const char* hbase = (const char*)hb;  // row = 128 B
    uint sv = *(const uint*)(hbase + (((uint)node << 7) + cb));
    f32x2 aA;                     // {f0,f1} (+ self on par 0)
    if (par == 0) aA = (f32x2){bflo(sv), bfhi(sv)};
    else          aA = (f32x2){0.f, 0.f};
    f32x2 bA = {0.f, 0.f};
    int cnt = nodeCnt[node];
    float dv = rsqrtf((float)(cnt + 1));
    const int* bp = esrc + nodeStart[node];
    int e = 0;
    if (cnt >= 16) {
        int s[8];
#pragma unroll
        for (int j = 0; j < 8; ++j) s[j] = bp[2 * j + par];
        while (true) {
            int sn[8];
#pragma unroll
            for (int j = 0; j < 8; ++j) sn[j] = bp[e + 16 + 2 * j + par];  // padded
            uint u[8];
#pragma unroll
            for (int j = 0; j < 8; ++j)
                u[j] = *(const uint*)(hbase + (((uint)s[j] << 7) + cb));
#pragma unroll
            for (int j = 0; j < 8; ++j) {
                f32x2 lo = {bflo(u[j]), bfhi(u[j])};
                if (j & 1) bA += lo;
                else       aA += lo;
            }
            e += 16;
            if (e + 16 > cnt) break;
#pragma unroll
            for (int j = 0; j < 8; ++j) s[j] = sn[j];
        }
    }
    if (e < cnt) {
        int last = cnt - 1;
        int s[8];
#pragma unroll
        for (int j = 0; j < 8; ++j) {
            int o = e + 2 * j + par;
            s[j] = bp[o < cnt ? o : last];
        }
        uint u[8];
#pragma unroll
        for (int j = 0; j < 8; ++j)
            u[j] = *(const uint*)(hbase + (((uint)s[j] << 7) + cb));
#pragma unroll
        for (int j = 0; j < 8; ++j) {
            float m = ((e + 2 * j + par) < cnt) ? 1.f : 0.f;
            f32x2 mm = {m, m};
            f32x2 lo = {bflo(u[j]), bfhi(u[j])};
            if (j & 1) bA += lo * mm;
            else       aA += lo * mm;
        }
    }
    aA += bA;
    float r0 = aA.x, r1 = aA.y;
    r0 += __shfl_xor(r0, 32);
    r1 += __shfl_xor(r1, 32);
    if (par == 0) {
        uint pk = (uint)f2bf(dv * r0) | ((uint)f2bf(dv * r1) << 16);
        ((uint*)out)[(size_t)node * 32 + (lane & 31)] = pk;
    }
}

// ---------------- BatchNorm stats: two-stage, NO global atomics ----------

__global__ __launch_bounds__(256) void col_partial_bf16_128(const ushort* __restrict__ a,
                                                            int M,
                                                            float* __restrict__ partials) {
    int col8 = threadIdx.x & 15;
    int rsub = threadIdx.x >> 4;
    const uint4* a4 = (const uint4*)a;
    float s[8], q[8];
#pragma unroll
    for (int i = 0; i < 8; ++i) { s[i] = 0.f; q[i] = 0.f; }
    for (int r = blockIdx.x * 16 + rsub; r < M; r += gridDim.x * 16) {
        uint4 v = a4[(size_t)r * 16 + col8];
        float f[8] = {bflo(v.x), bfhi(v.x), bflo(v.y), bfhi(v.y),
                      bflo(v.z), bfhi(v.z), bflo(v.w), bfhi(v.w)};
#pragma unroll
        for (int i = 0; i < 8; ++i) { s[i] += f[i]; q[i] += f[i] * f[i]; }
    }
    __shared__ float ls[256 * 8], lq[256 * 8];
#pragma unroll
    for (int i = 0; i < 8; ++i) {
        ls[threadIdx.x * 8 + i] = s[i];
        lq[threadIdx.x * 8 + i] = q[i];
    }
    __syncthreads();
    if (rsub == 0) {
        for (int t = col8 + 16; t < 256; t += 16) {
#pragma unroll
            for (int i = 0; i < 8; ++i) { s[i] += ls[t * 8 + i]; q[i] += lq[t * 8 + i]; }
        }
        float* ps = partials + (size_t)blockIdx.x * 256;
#pragma unroll
        for (int i = 0; i < 8; ++i) {
            ps[col8 * 8 + i] = s[i];
            ps[128 + col8 * 8 + i] = q[i];
        }
    }
}

__global__ __launch_bounds__(256) void col_partial_bf16_64(const ushort* __restrict__ a,
                                                           int M,
                                                           float* __restrict__ partials) {
    int col8 = threadIdx.x & 7;
    int rsub = threadIdx.x >> 3;
    const uint4* a4 = (const uint4*)a;
    float s[8], q[8];
#pragma unroll
    for (int i = 0; i < 8; ++i) { s[i] = 0.f; q[i] = 0.f; }
    for (int r = blockIdx.x * 32 + rsub; r < M; r += gridDim.x * 32) {
        uint4 v = a4[(size_t)r * 8 + col8];
        float f[8] = {bflo(v.x), bfhi(v.x), bflo(v.y), bfhi(v.y),
                      bflo(v.z), bfhi(v.z), bflo(v.w), bfhi(v.w)};
#pragma unroll
        for (int i = 0; i < 8; ++i) { s[i] += f[i]; q[i] += f[i] * f[i]; }
    }
    __shared__ float ls[256 * 8], lq[256 * 8];
#pragma unroll
    for (int i = 0; i < 8; ++i) {
        ls[threadIdx.x * 8 + i] = s[i];
        lq[threadIdx.x * 8 + i] = q[i];
    }
    __syncthreads();
    if (rsub == 0) {
        for (int t = col8 + 8; t < 256; t += 8) {
#pragma unroll
            for (int i = 0; i < 8; ++i) { s[i] += ls[t * 8 + i]; q[i] += lq[t * 8 + i]; }
        }
        float* ps = partials + (size_t)blockIdx.x * 128;
#pragma unroll
        for (int i = 0; i < 8; ++i) {
            ps[col8 * 8 + i] = s[i];
            ps[64 + col8 * 8 + i] = q[i];
        }
    }
}

// one block, 1024 threads: reduce CRB partials x 2F cols, emit scale/shift.
template <int F>
__global__ __launch_bounds__(1024) void col_finish(const float* __restrict__ partials,
                                                   int M,
                                                   const float* __restrict__ gamma,
                                                   const float* __restrict__ beta,
                                                   float* __restrict__ scale,
                                                   float* __restrict__ shift) {
    constexpr int C = 2 * F;          // 256 or 128 scalar cols
    constexpr int C4 = C / 4;         // 64 or 32 float4 cols
    constexpr int NCH = 1024 / C4;    // 16 or 32 row-chunks
    int t = threadIdx.x;
    int col4 = t % C4;
    int chunk = t / C4;
    const float4* p4 = (const float4*)partials;
    float4 a0 = make_float4(0.f, 0.f, 0.f, 0.f), a1 = a0, a2 = a0, a3 = a0;
    for (int b = chunk; b < CRB; b += 4 * NCH) {
        float4 v0 = p4[(size_t)(b + 0 * NCH) * C4 + col4];
        float4 v1 = p4[(size_t)(b + 1 * NCH) * C4 + col4];
        float4 v2 = p4[(size_t)(b + 2 * NCH) * C4 + col4];
        float4 v3 = p4[(size_t)(b + 3 * NCH) * C4 + col4];
        a0.x += v0.x; a0.y += v0.y; a0.z += v0.z; a0.w += v0.w;
        a1.x += v1.x; a1.y += v1.y; a1.z += v1.z; a1.w += v1.w;
        a2.x += v2.x; a2.y += v2.y; a2.z += v2.z; a2.w += v2.w;
        a3.x += v3.x; a3.y += v3.y; a3.z += v3.z; a3.w += v3.w;
    }
    a0.x += a1.x + a2.x + a3.x;
    a0.y += a1.y + a2.y + a3.y;
    a0.z += a1.z + a2.z + a3.z;
    a0.w += a1.w + a2.w + a3.w;
    __shared__ float4 red[1024];
    red[t] = a0;
    __syncthreads();
    __shared__ float fin[C];
    if (t < C4) {
        float4 s = red[t];
        for (int k = 1; k < NCH; ++k) {
            float4 v = red[t + k * C4];
            s.x += v.x; s.y += v.y; s.z += v.z; s.w += v.w;
        }
        fin[t * 4 + 0] = s.x;
        fin[t * 4 + 1] = s.y;
        fin[t * 4 + 2] = s.z;
        fin[t * 4 + 3] = s.w;
    }
    __syncthreads();
    if (t < F) {
        float mean = fin[t] / (float)M;
        float var = fin[F + t] / (float)M - mean * mean;
        float iv = rsqrtf(var + 1e-5f);
        float sc = gamma[t] * iv;
        scale[t] = sc;
        shift[t] = beta[t] - mean * sc;
    }
}

// apply BN2 to bf16 agg2, write f32 output
__global__ void apply_bn64b(const ushort* __restrict__ a, const float* __restrict__ scale,
                            const float* __restrict__ shift, float* __restrict__ out, int n4) {
    int i = blockIdx.x * blockDim.x + threadIdx.x;
    if (i >= n4) return;
    uint2 v = ((const uint2*)a)[i];   // 4 bf16 = features c0..c0+3
    int c0 = (i & 15) * 4;            // F=64 -> 16 uint2 per row
    float4 sc = *(const float4*)&scale[c0];
    float4 sh = *(const float4*)&shift[c0];
    float4 o;
    o.x = fmaf(bflo(v.x), sc.x, sh.x);
    o.y = fmaf(bfhi(v.x), sc.y, sh.y);
    o.z = fmaf(bflo(v.y), sc.z, sh.z);
    o.w = fmaf(bfhi(v.y), sc.w, sh.w);
    ((float4*)out)[i] = o;
}

// ---------------- launch ----------------

extern "C" void kernel_launch(void* const* d_in, const int* in_sizes, int n_in,
                              void* d_out, int out_size, void* d_ws, size_t ws_size,
                              hipStream_t stream) {
    const float* x      = (const float*)d_in[0];
    const float* W1     = (const float*)d_in[1];
    const float* gamma1 = (const float*)d_in[3];
    const float* beta1  = (const float*)d_in[4];
    const float* W2     = (const float*)d_in[5];
    const float* gamma2 = (const float*)d_in[7];
    const float* beta2  = (const float*)d_in[8];
    const int*   ei     = (const int*)d_in[9];

    const int hid  = in_sizes[2];            // 128
    const int outc = in_sizes[6];            // 64
    const int inc  = in_sizes[1] / hid;      // 128
    const int N    = in_sizes[0] / inc;      // 100000
    const int E    = in_sizes[9] / 2;        // 1600000
    const int* srcp = ei;
    const int* dstp = ei + E;
    const int NB   = (N + NPB - 1) >> SHIFT; // 196 for N=100000 (must be <= 256)
    const int chunk = (E + NB - 1) / NB;

    char* wsp = (char*)d_ws;
    size_t off = 0;
    auto alloc = [&](size_t bytes) -> void* {
        void* p = wsp + off;
        off += WS_ALIGN(bytes);
        return p;
    };
    int*   deg      = (int*)alloc((size_t)N * 4);        // zeroed below
    int*   ghist    = (int*)alloc((size_t)NB * NB * 4);
    int*   tot      = (int*)alloc((size_t)NB * 4);
    int*   parts    = (int*)alloc((size_t)E * 4);
    int*   esrc     = (int*)alloc((size_t)(E + 16) * 4);  // +16 pad for idx prefetch
    int*   nodeStart= (int*)alloc((size_t)N * 4);
    int*   nodeCnt  = (int*)alloc((size_t)N * 4);
    float* part1    = (float*)alloc((size_t)CRB * 2 * hid * 4);   // 1 MB
    float* part2    = (float*)alloc((size_t)CRB * 2 * outc * 4);  // 512 KB
    float* scale1   = (float*)alloc((size_t)hid * 4);
    float* shift1   = (float*)alloc((size_t)hid * 4);
    float* scale2   = (float*)alloc((size_t)outc * 4);
    float* shift2   = (float*)alloc((size_t)outc * 4);
    ushort* h1b     = (ushort*)alloc((size_t)N * hid * 2);     // bf16 hs1
    ushort* agg1b   = (ushort*)alloc((size_t)N * hid * 2);     // bf16 agg1
    ushort* h2b     = h1b;                 // h1b dead after spmm128
    ushort* agg2b   = agg1b;               // agg1b dead after gemm2 reads it

    hipMemsetAsync(deg, 0, (size_t)N * 4, stream);

    // CSR build + layer-1 GEMM overlapped (R11)
    p1_hist<<<NB, 256, 0, stream>>>(dstp, E, chunk, NB, ghist, deg);
    p1_colscan<<<NB, 256, 0, stream>>>(ghist, NB, tot);
    k_place_gemm1<<<NB + (N + 63) / 64, 256, 0, stream>>>(
        srcp, dstp, E, chunk, NB, ghist, tot, parts, x, W1, deg, h1b, N);
    p2_csr<<<NB, 256, 0, stream>>>(parts, tot, NB, N, nodeStart, nodeCnt, esrc);

    // layer 1 aggregate + BN1 stats
    spmm128<<<(N + 3) / 4, 256, 0, stream>>>(h1b, nodeStart, nodeCnt, esrc, agg1b, N);
    col_partial_bf16_128<<<CRB, 256, 0, stream>>>(agg1b, N, part1);
    col_finish<128><<<1, 1024, 0, stream>>>(part1, N, gamma1, beta1, scale1, shift1);

    // layer 2
    k_gemm2<<<(N + 63) / 64, 256, 0, stream>>>(agg1b, W2, scale1, shift1, deg, h2b, N);
    spmm64<<<(N + 3) / 4, 256, 0, stream>>>(h2b, nodeStart, nodeCnt, esrc, agg2b, N);
    col_partial_bf16_64<<<CRB, 256, 0, stream>>>(agg2b, N, part2);
    col_finish<64><<<1, 1024, 0, stream>>>(part2, N, gamma2, beta2, scale2, shift2);
    apply_bn64b<<<(N * 64 / 4 + 255) / 256, 256, 0, stream>>>(agg2b, scale2, shift2,
                                                              (float*)d_out, N * 64 / 4);
}

// Round 13
// 341.798 us; speedup vs baseline: 1.1415x; 1.1415x over previous
//
#include <hip/hip_runtime.h>

#define WS_ALIGN(x) (((x) + size_t(255)) & ~size_t(255))

typedef unsigned int uint;
typedef unsigned short ushort;
typedef __attribute__((ext_vector_type(8))) short short8;
typedef __attribute__((ext_vector_type(4))) float floatx4;
typedef __attribute__((ext_vector_type(2))) float f32x2;   // v_pk_*_f32

#define SHIFT 9          // 512 nodes per coarse bucket
#define NPB   (1 << SHIFT)
#define CRB   1024       // col-reduce stage-1 blocks (R5 proven config)

__device__ __forceinline__ ushort f2bf(float f) {
    uint u = __float_as_uint(f);
    return (ushort)((u + 0x7fff + ((u >> 16) & 1)) >> 16);  // RNE
}
__device__ __forceinline__ float bflo(uint u) { return __uint_as_float(u << 16); }
__device__ __forceinline__ float bfhi(uint u) { return __uint_as_float(u & 0xffff0000u); }

// ---------------- CSR build: LDS-radix partition (no global atomics) ----------
// Requires N <= 131072 (src packs in 17 bits) and NB <= 256.
// R12 lesson: per-node deg via global atomicAdd = 68us (random-address
// atomics dirty 50MB of lines at 7% occupancy). LDS-radix only; no global
// atomics anywhere in the CSR build.

__global__ __launch_bounds__(256) void p1_hist(const int* __restrict__ dst, int E,
                                               int chunk, int NB, int* __restrict__ ghist) {
    __shared__ int h[256];
    h[threadIdx.x] = 0;
    __syncthreads();
    int e0 = blockIdx.x * chunk, e1 = min(E, e0 + chunk);
    for (int e = e0 + threadIdx.x; e < e1; e += 256)
        atomicAdd(&h[dst[e] >> SHIFT], 1);
    __syncthreads();
    if ((int)threadIdx.x < NB) ghist[blockIdx.x * NB + threadIdx.x] = h[threadIdx.x];
}

// block c: exclusive prefix down column c of ghist[NB][NB]; total -> tot[c]
__global__ __launch_bounds__(256) void p1_colscan(int* __restrict__ ghist, int NB,
                                                  int* __restrict__ tot) {
    __shared__ int lds[256];
    int c = blockIdx.x, t = threadIdx.x;
    int v = (t < NB) ? ghist[t * NB + c] : 0;
    lds[t] = v;
    __syncthreads();
    for (int o = 1; o < 256; o <<= 1) {
        int u = (t >= o) ? lds[t - o] : 0;
        __syncthreads();
        if (t >= o) lds[t] += u;
        __syncthreads();
    }
    if (t < NB) ghist[t * NB + c] = lds[t] - v;  // exclusive over blocks
    if (t == 255) tot[c] = lds[255];
}

__global__ __launch_bounds__(256) void p1_base(const int* __restrict__ tot, int NB,
                                               int* __restrict__ bbase) {
    __shared__ int lds[256];
    int t = threadIdx.x;
    int v = (t < NB) ? tot[t] : 0;
    lds[t] = v;
    __syncthreads();
    for (int o = 1; o < 256; o <<= 1) {
        int u = (t >= o) ? lds[t - o] : 0;
        __syncthreads();
        if (t >= o) lds[t] += u;
        __syncthreads();
    }
    if (t < NB) bbase[t] = lds[t] - v;
    if (t == 255) bbase[NB] = lds[255];  // = E
}

__global__ __launch_bounds__(256) void p1_place(const int* __restrict__ src,
                                                const int* __restrict__ dst, int E,
                                                int chunk, int NB,
                                                const int* __restrict__ ghist,
                                                const int* __restrict__ bbase,
                                                int* __restrict__ parts) {
    __shared__ int h[256];
    __shared__ int base[256];
    int t = threadIdx.x;
    h[t] = 0;
    if (t < NB) base[t] = bbase[t] + ghist[blockIdx.x * NB + t];
    __syncthreads();
    int e0 = blockIdx.x * chunk, e1 = min(E, e0 + chunk);
    for (int e = e0 + t; e < e1; e += 256) {
        int d = dst[e];
        int b = d >> SHIFT;
        int local = atomicAdd(&h[b], 1);
        parts[base[b] + local] = src[e] | ((d & (NPB - 1)) << 17);
    }
}

// one block per bucket: local count -> scan -> CSR place; export start/cnt/dinv
__global__ __launch_bounds__(256) void p2_csr(const int* __restrict__ parts,
                                              const int* __restrict__ bbase, int N,
                                              int* __restrict__ nodeStart,
                                              int* __restrict__ nodeCnt,
                                              float* __restrict__ dinv,
                                              int* __restrict__ esrc) {
    __shared__ int cnt[NPB], off[NPB], cur[NPB];
    __shared__ int pair[256];
    int b = blockIdx.x, t = threadIdx.x;
    int n0 = b << SHIFT;
    cnt[t] = 0;
    cnt[t + 256] = 0;
    cur[t] = 0;
    cur[t + 256] = 0;
    __syncthreads();
    int e0 = bbase[b], e1 = bbase[b + 1];
    for (int e = e0 + t; e < e1; e += 256)
        atomicAdd(&cnt[(parts[e] >> 17) & (NPB - 1)], 1);
    __syncthreads();
    int psum = cnt[2 * t] + cnt[2 * t + 1];
    pair[t] = psum;
    __syncthreads();
    for (int o = 1; o < 256; o <<= 1) {
        int u = (t >= o) ? pair[t - o] : 0;
        __syncthreads();
        if (t >= o) pair[t] += u;
        __syncthreads();
    }
    int excl = pair[t] - psum;
    off[2 * t] = excl;
    off[2 * t + 1] = excl + cnt[2 * t];
    __syncthreads();
#pragma unroll
    for (int j = t; j < NPB; j += 256) {
        int n = n0 + j;
        if (n < N) {
            nodeStart[n] = e0 + off[j];
            nodeCnt[n] = cnt[j];
            dinv[n] = rsqrtf((float)(cnt[j] + 1));  // +1 self-loop (fused)
        }
    }
    for (int e = e0 + t; e < e1; e += 256) {
        int p = parts[e];
        int dl = (p >> 17) & (NPB - 1);
        int local = atomicAdd(&cur[dl], 1);
        esrc[e0 + off[dl] + local] = p & 0x1FFFF;
    }
}

// ---------------- W pre-convert: fp32 [k][n] -> bf16 [n][k] ----------------

__global__ void wconv(const float* __restrict__ W1, const float* __restrict__ W2,
                      ushort* __restrict__ W1t, ushort* __restrict__ W2t) {
    int i = blockIdx.x * blockDim.x + threadIdx.x;
    if (i < 128 * 128) {
        int n = i >> 7, k = i & 127;
        W1t[i] = f2bf(W1[k * 128 + n]);
    }
    int j = i - 128 * 128;
    if (j >= 0 && j < 64 * 128) {
        int n = j >> 7, k = j & 127;
        W2t[j] = f2bf(W2[k * 64 + n]);
    }
}

// ---------------- MFMA bf16 GEMM (K=128), optional fused BN+ReLU on A ------
// ABF16: A is bf16 [M][128] (agg1 path) — halves A-staging traffic.

template <int TN, bool BN, bool ABF16>
__global__ __launch_bounds__(256) void gemm_mfma(const void* __restrict__ Araw,
                                                 const ushort* __restrict__ Wt,
                                                 const float* __restrict__ scale,
                                                 const float* __restrict__ shift,
                                                 const float* __restrict__ dinv,
                                                 ushort* __restrict__ Cb, int M) {
    constexpr int TM = 64;
    constexpr int PK = 136;  // padded row stride in shorts: 272 B (16B-aligned)
    constexpr int NCT = TN / 16;
    __shared__ ushort Ab[TM * PK];
    __shared__ ushort Wl[TN * PK];
    int tid = threadIdx.x;
    int wave = tid >> 6, lane = tid & 63;
    int rowBase = blockIdx.x * TM;

    for (int l = tid; l < TN * 16; l += 256) {
        int n = l >> 4, c = (l & 15) << 3;
        *(uint4*)&Wl[n * PK + c] = *(const uint4*)&Wt[n * 128 + c];
    }
    if constexpr (ABF16) {
        const ushort* A = (const ushort*)Araw;
        for (int l = tid; l < TM * 16; l += 256) {
            int r = l >> 4, c = (l & 15) << 3;   // 8 bf16 per thread
            int gr = rowBase + r;
            uint4 v = make_uint4(0, 0, 0, 0);
            if (gr < M) v = *(const uint4*)&A[(size_t)gr * 128 + c];
            if (BN) {
                uint w[4] = {v.x, v.y, v.z, v.w};
                uint o[4];
#pragma unroll
                for (int k = 0; k < 4; ++k) {
                    float f0 = fmaxf(fmaf(bflo(w[k]), scale[c + 2 * k], shift[c + 2 * k]), 0.f);
                    float f1 = fmaxf(fmaf(bfhi(w[k]), scale[c + 2 * k + 1], shift[c + 2 * k + 1]), 0.f);
                    o[k] = (uint)f2bf(f0) | ((uint)f2bf(f1) << 16);
                }
                v = make_uint4(o[0], o[1], o[2], o[3]);
            }
            *(uint4*)&Ab[r * PK + c] = v;
        }
    } else {
        const float* A = (const float*)Araw;
        for (int l = tid; l < TM * 32; l += 256) {
            int r = l >> 5, c = (l & 31) << 2;
            int gr = rowBase + r;
            float4 v = make_float4(0.f, 0.f, 0.f, 0.f);
            if (gr < M) v = *(const float4*)&A[(size_t)gr * 128 + c];
            if (BN) {
                v.x = fmaxf(fmaf(v.x, scale[c + 0], shift[c + 0]), 0.f);
                v.y = fmaxf(fmaf(v.y, scale[c + 1], shift[c + 1]), 0.f);
                v.z = fmaxf(fmaf(v.z, scale[c + 2], shift[c + 2]), 0.f);
                v.w = fmaxf(fmaf(v.w, scale[c + 3], shift[c + 3]), 0.f);
            }
            uint2 p;
            p.x = (uint)f2bf(v.x) | ((uint)f2bf(v.y) << 16);
            p.y = (uint)f2bf(v.z) | ((uint)f2bf(v.w) << 16);
            *(uint2*)&Ab[r * PK + c] = p;
        }
    }
    __syncthreads();

    floatx4 acc[NCT];
#pragma unroll
    for (int ct = 0; ct < NCT; ++ct) acc[ct] = (floatx4){0.f, 0.f, 0.f, 0.f};

    int m = wave * 16 + (lane & 15);
    int quad = lane >> 4;
#pragma unroll
    for (int kc = 0; kc < 128; kc += 32) {
        int k0 = kc + quad * 8;
        short8 a = *(const short8*)&Ab[m * PK + k0];
#pragma unroll
        for (int ct = 0; ct < NCT; ++ct) {
            short8 b = *(const short8*)&Wl[(ct * 16 + (lane & 15)) * PK + k0];
            acc[ct] = __builtin_amdgcn_mfma_f32_16x16x32_bf16(a, b, acc[ct], 0, 0, 0);
        }
    }

    int r0 = rowBase + wave * 16 + quad * 4;
    int col0 = lane & 15;
#pragma unroll
    for (int r = 0; r < 4; ++r) {
        int gr = r0 + r;
        if (gr < M) {
            float dv = dinv[gr];
#pragma unroll
            for (int ct = 0; ct < NCT; ++ct)
                Cb[(size_t)gr * TN + ct * 16 + col0] = f2bf(acc[ct][r] * dv);
        }
    }
}

// ---------------- SpMM: unweighted gather-sum of hs rows, scale by dinv ----
// R5 structure (proven best) + R8 packed-f32 accumulation.
// R9: agg1 stored bf16. R10: agg2 also bf16.

__global__ __launch_bounds__(256) void spmm128(const ushort* __restrict__ hb,
                                               const int* __restrict__ nodeStart,
                                               const int* __restrict__ nodeCnt,
                                               const int* __restrict__ esrc,
                                               const float* __restrict__ dinv,
                                               ushort* __restrict__ out, int N) {
    int node = blockIdx.x * 4 + (threadIdx.x >> 6);
    if (node >= N) return;
    int lane = threadIdx.x & 63;
    int par = lane >> 5;          // 0: even edges, 1: odd edges
    int cb = (lane & 31) << 3;    // byte offset of this lane's uint2 column
    const char* hbase = (const char*)hb;  // row = 256 B
    uint2 sv = *(const uint2*)(hbase + (((uint)node << 8) + cb));
    f32x2 aA, aB;                 // even chain {f0,f1},{f2,f3} (+ self on par 0)
    if (par == 0) {
        aA = (f32x2){bflo(sv.x), bfhi(sv.x)};
        aB = (f32x2){bflo(sv.y), bfhi(sv.y)};
    } else {
        aA = (f32x2){0.f, 0.f};
        aB = (f32x2){0.f, 0.f};
    }
    f32x2 bA = {0.f, 0.f}, bB = {0.f, 0.f};  // odd chain (ILP)
    int cnt = nodeCnt[node];
    const int* bp = esrc + nodeStart[node];
    int e = 0;
    if (cnt >= 16) {
        int s[8];
#pragma unroll
        for (int j = 0; j < 8; ++j) s[j] = bp[2 * j + par];
        while (true) {
            int sn[8];
#pragma unroll
            for (int j = 0; j < 8; ++j) sn[j] = bp[e + 16 + 2 * j + par];  // padded
            uint2 u[8];
#pragma unroll
            for (int j = 0; j < 8; ++j)
                u[j] = *(const uint2*)(hbase + (((uint)s[j] << 8) + cb));
#pragma unroll
            for (int j = 0; j < 8; ++j) {
                f32x2 lo = {bflo(u[j].x), bfhi(u[j].x)};
                f32x2 hi = {bflo(u[j].y), bfhi(u[j].y)};
                if (j & 1) { bA += lo; bB += hi; }
                else       { aA += lo; aB += hi; }
            }
            e += 16;
            if (e + 16 > cnt) break;
#pragma unroll
            for (int j = 0; j < 8; ++j) s[j] = sn[j];
        }
    }
    if (e < cnt) {  // batched predicated tail: one parallel round trip
        int last = cnt - 1;
        int s[8];
#pragma unroll
        for (int j = 0; j < 8; ++j) {
            int o = e + 2 * j + par;
            s[j] = bp[o < cnt ? o : last];
        }
        uint2 u[8];
#pragma unroll
        for (int j = 0; j < 8; ++j)
            u[j] = *(const uint2*)(hbase + (((uint)s[j] << 8) + cb));
#pragma unroll
        for (int j = 0; j < 8; ++j) {
            float m = ((e + 2 * j + par) < cnt) ? 1.f : 0.f;
            f32x2 mm = {m, m};
            f32x2 lo = {bflo(u[j].x), bfhi(u[j].x)};
            f32x2 hi = {bflo(u[j].y), bfhi(u[j].y)};
            if (j & 1) { bA += lo * mm; bB += hi * mm; }
            else       { aA += lo * mm; aB += hi * mm; }
        }
    }
    aA += bA;
    aB += bB;
    float r0 = aA.x, r1 = aA.y, r2 = aB.x, r3 = aB.y;
    r0 += __shfl_xor(r0, 32);
    r1 += __shfl_xor(r1, 32);
    r2 += __shfl_xor(r2, 32);
    r3 += __shfl_xor(r3, 32);
    if (par == 0) {
        float dv = dinv[node];
        uint2 pk;
        pk.x = (uint)f2bf(dv * r0) | ((uint)f2bf(dv * r1) << 16);
        pk.y = (uint)f2bf(dv * r2) | ((uint)f2bf(dv * r3) << 16);
        ((uint2*)out)[(size_t)node * 32 + (lane & 31)] = pk;
    }
}

__global__ __launch_bounds__(256) void spmm64(const ushort* __restrict__ hb,
                                              const int* __restrict__ nodeStart,
                                              const int* __restrict__ nodeCnt,
                                              const int* __restrict__ esrc,
                                              const float* __restrict__ dinv,
                                              ushort* __restrict__ out, int N) {
    int node = blockIdx.x * 4 + (threadIdx.x >> 6);
    if (node >= N) return;
    int lane = threadIdx.x & 63;
    int par = lane >> 5;          // 0: even edges, 1: odd edges
    int cb = (lane & 31) << 2;    // byte offset of this lane's uint column
    const char* hbase = (const char*)hb;  // row = 128 B
    uint sv = *(const uint*)(hbase + (((uint)node << 7) + cb));
    f32x2 aA;                     // {f0,f1} (+ self on par 0)
    if (par == 0) aA = (f32x2){bflo(sv), bfhi(sv)};
    else          aA = (f32x2){0.f, 0.f};
    f32x2 bA = {0.f, 0.f};
    int cnt = nodeCnt[node];
    const int* bp = esrc + nodeStart[node];
    int e = 0;
    if (cnt >= 16) {
        int s[8];
#pragma unroll
        for (int j = 0; j < 8; ++j) s[j] = bp[2 * j + par];
        while (true) {
            int sn[8];
#pragma unroll
            for (int j = 0; j < 8; ++j) sn[j] = bp[e + 16 + 2 * j + par];  // padded
            uint u[8];
#pragma unroll
            for (int j = 0; j < 8; ++j)
                u[j] = *(const uint*)(hbase + (((uint)s[j] << 7) + cb));
#pragma unroll
            for (int j = 0; j < 8; ++j) {
                f32x2 lo = {bflo(u[j]), bfhi(u[j])};
                if (j & 1) bA += lo;
                else       aA += lo;
            }
            e += 16;
            if (e + 16 > cnt) break;
#pragma unroll
            for (int j = 0; j < 8; ++j) s[j] = sn[j];
        }
    }
    if (e < cnt) {
        int last = cnt - 1;
        int s[8];
#pragma unroll
        for (int j = 0; j < 8; ++j) {
            int o = e + 2 * j + par;
            s[j] = bp[o < cnt ? o : last];
        }
        uint u[8];
#pragma unroll
        for (int j = 0; j < 8; ++j)
            u[j] = *(const uint*)(hbase + (((uint)s[j] << 7) + cb));
#pragma unroll
        for (int j = 0; j < 8; ++j) {
            float m = ((e + 2 * j + par) < cnt) ? 1.f : 0.f;
            f32x2 mm = {m, m};
            f32x2 lo = {bflo(u[j]), bfhi(u[j])};
            if (j & 1) bA += lo * mm;
            else       aA += lo * mm;
        }
    }
    aA += bA;
    float r0 = aA.x, r1 = aA.y;
    r0 += __shfl_xor(r0, 32);
    r1 += __shfl_xor(r1, 32);
    if (par == 0) {
        float dv = dinv[node];
        uint pk = (uint)f2bf(dv * r0) | ((uint)f2bf(dv * r1) << 16);
        ((uint*)out)[(size_t)node * 32 + (lane & 31)] = pk;
    }
}

// ---------------- BatchNorm stats: two-stage, NO global atomics ----------
// Stage 1 writes per-block partials (R3 lesson). bf16 input variants.

__global__ __launch_bounds__(256) void col_partial_bf16_128(const ushort* __restrict__ a,
                                                            int M,
                                                            float* __restrict__ partials) {
    // row = 128 bf16 = 16 uint4; 16 col-groups x 16 rows in flight
    int col8 = threadIdx.x & 15;
    int rsub = threadIdx.x >> 4;
    const uint4* a4 = (const uint4*)a;
    float s[8], q[8];
#pragma unroll
    for (int i = 0; i < 8; ++i) { s[i] = 0.f; q[i] = 0.f; }
    for (int r = blockIdx.x * 16 + rsub; r < M; r += gridDim.x * 16) {
        uint4 v = a4[(size_t)r * 16 + col8];
        float f[8] = {bflo(v.x), bfhi(v.x), bflo(v.y), bfhi(v.y),
                      bflo(v.z), bfhi(v.z), bflo(v.w), bfhi(v.w)};
#pragma unroll
        for (int i = 0; i < 8; ++i) { s[i] += f[i]; q[i] += f[i] * f[i]; }
    }
    __shared__ float ls[256 * 8], lq[256 * 8];
#pragma unroll
    for (int i = 0; i < 8; ++i) {
        ls[threadIdx.x * 8 + i] = s[i];
        lq[threadIdx.x * 8 + i] = q[i];
    }
    __syncthreads();
    if (rsub == 0) {
        for (int t = col8 + 16; t < 256; t += 16) {
#pragma unroll
            for (int i = 0; i < 8; ++i) { s[i] += ls[t * 8 + i]; q[i] += lq[t * 8 + i]; }
        }
        float* ps = partials + (size_t)blockIdx.x * 256;
#pragma unroll
        for (int i = 0; i < 8; ++i) {
            ps[col8 * 8 + i] = s[i];
            ps[128 + col8 * 8 + i] = q[i];
        }
    }
}

__global__ __launch_bounds__(256) void col_partial_bf16_64(const ushort* __restrict__ a,
                                                           int M,
                                                           float* __restrict__ partials) {
    // row = 64 bf16 = 8 uint4; 8 col-groups x 32 rows in flight
    int col8 = threadIdx.x & 7;
    int rsub = threadIdx.x >> 3;
    const uint4* a4 = (const uint4*)a;
    float s[8], q[8];
#pragma unroll
    for (int i = 0; i < 8; ++i) { s[i] = 0.f; q[i] = 0.f; }
    for (int r = blockIdx.x * 32 + rsub; r < M; r += gridDim.x * 32) {
        uint4 v = a4[(size_t)r * 8 + col8];
        float f[8] = {bflo(v.x), bfhi(v.x), bflo(v.y), bfhi(v.y),
                      bflo(v.z), bfhi(v.z), bflo(v.w), bfhi(v.w)};
#pragma unroll
        for (int i = 0; i < 8; ++i) { s[i] += f[i]; q[i] += f[i] * f[i]; }
    }
    __shared__ float ls[256 * 8], lq[256 * 8];
#pragma unroll
    for (int i = 0; i < 8; ++i) {
        ls[threadIdx.x * 8 + i] = s[i];
        lq[threadIdx.x * 8 + i] = q[i];
    }
    __syncthreads();
    if (rsub == 0) {
        for (int t = col8 + 8; t < 256; t += 8) {
#pragma unroll
            for (int i = 0; i < 8; ++i) { s[i] += ls[t * 8 + i]; q[i] += lq[t * 8 + i]; }
        }
        float* ps = partials + (size_t)blockIdx.x * 128;
#pragma unroll
        for (int i = 0; i < 8; ++i) {
            ps[col8 * 8 + i] = s[i];
            ps[64 + col8 * 8 + i] = q[i];
        }
    }
}

// one block, 1024 threads: reduce CRB partials x 2F cols, emit scale/shift.
template <int F>
__global__ __launch_bounds__(1024) void col_finish(const float* __restrict__ partials,
                                                   int M,
                                                   const float* __restrict__ gamma,
                                                   const float* __restrict__ beta,
                                                   float* __restrict__ scale,
                                                   float* __restrict__ shift) {
    constexpr int C = 2 * F;          // 256 or 128 scalar cols
    constexpr int C4 = C / 4;         // 64 or 32 float4 cols
    constexpr int NCH = 1024 / C4;    // 16 or 32 row-chunks
    int t = threadIdx.x;
    int col4 = t % C4;
    int chunk = t / C4;
    const float4* p4 = (const float4*)partials;
    float4 a0 = make_float4(0.f, 0.f, 0.f, 0.f), a1 = a0, a2 = a0, a3 = a0;
    for (int b = chunk; b < CRB; b += 4 * NCH) {
        float4 v0 = p4[(size_t)(b + 0 * NCH) * C4 + col4];
        float4 v1 = p4[(size_t)(b + 1 * NCH) * C4 + col4];
        float4 v2 = p4[(size_t)(b + 2 * NCH) * C4 + col4];
        float4 v3 = p4[(size_t)(b + 3 * NCH) * C4 + col4];
        a0.x += v0.x; a0.y += v0.y; a0.z += v0.z; a0.w += v0.w;
        a1.x += v1.x; a1.y += v1.y; a1.z += v1.z; a1.w += v1.w;
        a2.x += v2.x; a2.y += v2.y; a2.z += v2.z; a2.w += v2.w;
        a3.x += v3.x; a3.y += v3.y; a3.z += v3.z; a3.w += v3.w;
    }
    a0.x += a1.x + a2.x + a3.x;
    a0.y += a1.y + a2.y + a3.y;
    a0.z += a1.z + a2.z + a3.z;
    a0.w += a1.w + a2.w + a3.w;
    __shared__ float4 red[1024];
    red[t] = a0;
    __syncthreads();
    __shared__ float fin[C];
    if (t < C4) {
        float4 s = red[t];
        for (int k = 1; k < NCH; ++k) {
            float4 v = red[t + k * C4];
            s.x += v.x; s.y += v.y; s.z += v.z; s.w += v.w;
        }
        fin[t * 4 + 0] = s.x;
        fin[t * 4 + 1] = s.y;
        fin[t * 4 + 2] = s.z;
        fin[t * 4 + 3] = s.w;
    }
    __syncthreads();
    if (t < F) {
        float mean = fin[t] / (float)M;
        float var = fin[F + t] / (float)M - mean * mean;
        float iv = rsqrtf(var + 1e-5f);
        float sc = gamma[t] * iv;
        scale[t] = sc;
        shift[t] = beta[t] - mean * sc;
    }
}

// apply BN2 to bf16 agg2, write f32 output
__global__ void apply_bn64b(const ushort* __restrict__ a, const float* __restrict__ scale,
                            const float* __restrict__ shift, float* __restrict__ out, int n4) {
    int i = blockIdx.x * blockDim.x + threadIdx.x;
    if (i >= n4) return;
    uint2 v = ((const uint2*)a)[i];   // 4 bf16 = features c0..c0+3
    int c0 = (i & 15) * 4;            // F=64 -> 16 uint2 per row
    float4 sc = *(const float4*)&scale[c0];
    float4 sh = *(const float4*)&shift[c0];
    float4 o;
    o.x = fmaf(bflo(v.x), sc.x, sh.x);
    o.y = fmaf(bfhi(v.x), sc.y, sh.y);
    o.z = fmaf(bflo(v.y), sc.z, sh.z);
    o.w = fmaf(bfhi(v.y), sc.w, sh.w);
    ((float4*)out)[i] = o;
}

// ---------------- launch ----------------

extern "C" void kernel_launch(void* const* d_in, const int* in_sizes, int n_in,
                              void* d_out, int out_size, void* d_ws, size_t ws_size,
                              hipStream_t stream) {
    const float* x      = (const float*)d_in[0];
    const float* W1     = (const float*)d_in[1];
    const float* gamma1 = (const float*)d_in[3];
    const float* beta1  = (const float*)d_in[4];
    const float* W2     = (const float*)d_in[5];
    const float* gamma2 = (const float*)d_in[7];
    const float* beta2  = (const float*)d_in[8];
    const int*   ei     = (const int*)d_in[9];

    const int hid  = in_sizes[2];            // 128
    const int outc = in_sizes[6];            // 64
    const int inc  = in_sizes[1] / hid;      // 128
    const int N    = in_sizes[0] / inc;      // 100000
    const int E    = in_sizes[9] / 2;        // 1600000
    const int* srcp = ei;
    const int* dstp = ei + E;
    const int NB   = (N + NPB - 1) >> SHIFT; // 196 for N=100000 (must be <= 256)
    const int chunk = (E + NB - 1) / NB;

    char* wsp = (char*)d_ws;
    size_t off = 0;
    auto alloc = [&](size_t bytes) -> void* {
        void* p = wsp + off;
        off += WS_ALIGN(bytes);
        return p;
    };
    int*   ghist    = (int*)alloc((size_t)NB * NB * 4);
    int*   tot      = (int*)alloc((size_t)NB * 4);
    int*   bbase    = (int*)alloc((size_t)(NB + 1) * 4);
    int*   parts    = (int*)alloc((size_t)E * 4);
    int*   esrc     = (int*)alloc((size_t)(E + 16) * 4);  // +16 pad for idx prefetch
    int*   nodeStart= (int*)alloc((size_t)N * 4);
    int*   nodeCnt  = (int*)alloc((size_t)N * 4);
    float* dinv     = (float*)alloc((size_t)N * 4);
    float* part1    = (float*)alloc((size_t)CRB * 2 * hid * 4);   // 1 MB
    float* part2    = (float*)alloc((size_t)CRB * 2 * outc * 4);  // 512 KB
    float* scale1   = (float*)alloc((size_t)hid * 4);
    float* shift1   = (float*)alloc((size_t)hid * 4);
    float* scale2   = (float*)alloc((size_t)outc * 4);
    float* shift2   = (float*)alloc((size_t)outc * 4);
    ushort* W1t     = (ushort*)alloc((size_t)hid * inc * 2);   // bf16 [n][k]
    ushort* W2t     = (ushort*)alloc((size_t)outc * hid * 2);  // bf16 [n][k]
    ushort* h1b     = (ushort*)alloc((size_t)N * hid * 2);     // bf16 hs1
    ushort* agg1b   = (ushort*)alloc((size_t)N * hid * 2);     // bf16 agg1 (R9)
    ushort* h2b     = h1b;                 // h1b dead after spmm128
    ushort* agg2b   = agg1b;               // agg1b dead after gemm2 reads it (R10)

    // CSR build: LDS-radix, zero global atomics (dinv fused into p2_csr)
    p1_hist<<<NB, 256, 0, stream>>>(dstp, E, chunk, NB, ghist);
    p1_colscan<<<NB, 256, 0, stream>>>(ghist, NB, tot);
    p1_base<<<1, 256, 0, stream>>>(tot, NB, bbase);
    p1_place<<<NB, 256, 0, stream>>>(srcp, dstp, E, chunk, NB, ghist, bbase, parts);
    p2_csr<<<NB, 256, 0, stream>>>(parts, bbase, N, nodeStart, nodeCnt, dinv, esrc);
    wconv<<<(128 * 128 + 64 * 128 + 255) / 256, 256, 0, stream>>>(W1, W2, W1t, W2t);

    // layer 1: hs1 = dinv * (x @ W1) (bf16) ; agg1(bf16) = dinv*(self+gather) ; BN1
    gemm_mfma<128, false, false><<<(N + 63) / 64, 256, 0, stream>>>(
        x, W1t, nullptr, nullptr, dinv, h1b, N);
    spmm128<<<(N + 3) / 4, 256, 0, stream>>>(h1b, nodeStart, nodeCnt, esrc, dinv, agg1b, N);
    col_partial_bf16_128<<<CRB, 256, 0, stream>>>(agg1b, N, part1);
    col_finish<128><<<1, 1024, 0, stream>>>(part1, N, gamma1, beta1, scale1, shift1);

    // layer 2 (A = bf16 agg1, BN+ReLU fused in staging; agg2 bf16)
    gemm_mfma<64, true, true><<<(N + 63) / 64, 256, 0, stream>>>(
        agg1b, W2t, scale1, shift1, dinv, h2b, N);
    spmm64<<<(N + 3) / 4, 256, 0, stream>>>(h2b, nodeStart, nodeCnt, esrc, dinv, agg2b, N);
    col_partial_bf16_64<<<CRB, 256, 0, stream>>>(agg2b, N, part2);
    col_finish<64><<<1, 1024, 0, stream>>>(part2, N, gamma2, beta2, scale2, shift2);
    apply_bn64b<<<(N * 64 / 4 + 255) / 256, 256, 0, stream>>>(agg2b, scale2, shift2,
                                                              (float*)d_out, N * 64 / 4);
}